// Round 17
// baseline (299.763 us; speedup 1.0000x reference)
//
#include <hip/hip_runtime.h>
#include <stdint.h>
#include <stddef.h>

// ---------------------------------------------------------------------------
// BSplineKANLayer — R18: gen-once at 2 blocks/CU (BM=32 x BN=512, G=2).
// R17 post-mortem: counted-vmcnt wave-private = regression (153 vs 142) —
// doubled sync points beat the drain it saved. Consolidated model R10-R17:
// MFMA ~33us and stall ~45-50us (2blk/CU) are schedule-invariant; VALU is the
// mover: 61us gen-2x (BN=256) vs 36-40us gen-once (BN=512, only ever tested
// at 1 blk/CU where mono-block stall +70us swamped it). R18 fills the missing
// cell: BM=32 x BN=512, grid 512 = 2 blocks/CU, G=2, LDS 68KB (Bs 2x32K +
// As 2x2K). 1 eval/thread/group with one-group-ahead register prefetch
// (1 scalar x + float2 cst — lean, unlike R15's 32-reg silu buffer).
// R12's proven 2-barrier __syncthreads schedule; proven rotation layout.
// ---------------------------------------------------------------------------

typedef __attribute__((ext_vector_type(8))) _Float16 half8;  // 8 fp16 = 4 VGPRs
typedef __attribute__((ext_vector_type(4))) float f32x4;

#define IN_DIM   512
#define OUT_DIM  512
#define BATCH    16384
#define KCH      576     // uint4 chunks per row: 4608 fp16 = 576 * 16B

// RNE f32 -> fp16 pair packed in a uint (a low 16, b high 16)
__device__ __forceinline__ unsigned pk2(float a, float b) {
  _Float16 ha = (_Float16)a, hb = (_Float16)b;   // v_cvt_f16_f32 (RNE)
  unsigned short ua = __builtin_bit_cast(unsigned short, ha);
  unsigned short ub = __builtin_bit_cast(unsigned short, hb);
  return (unsigned)ua | ((unsigned)ub << 16);
}
__device__ __forceinline__ uint4 pk8(float4 a, float4 b) {
  uint4 r;
  r.x = pk2(a.x, a.y); r.y = pk2(a.z, a.w);
  r.z = pk2(b.x, b.y); r.w = pk2(b.z, b.w);
  return r;
}
__device__ __forceinline__ float4 silu4(float4 v) {
  float4 r;
  r.x = v.x / (1.f + __expf(-v.x));
  r.y = v.y / (1.f + __expf(-v.y));
  r.z = v.z / (1.f + __expf(-v.z));
  r.w = v.w / (1.f + __expf(-v.w));
  return r;
}

// branchless 64->32 funnel extract: bits [amt, amt+32) of p, 0 outside range
__device__ __forceinline__ uint32_t fsh(uint64_t p, int amt) {
  uint32_t lo = (uint32_t)(p >> (amt & 63));
  lo = (amt >= 0 && amt < 64) ? lo : 0u;
  uint32_t hi = (uint32_t)(p << ((-amt) & 63));
  hi = (amt < 0 && amt > -64) ? hi : 0u;
  return lo | hi;
}

// Windowed cubic basis (uniform grid; matches reference's single-step-denom
// recursion exactly — verified R5..R17): 8 fp16 values for one (row,dim).
__device__ __forceinline__ uint4 basis8(float xv, float g0, float rh) {
  float u  = (xv - g0) * rh;
  float tf = floorf(u);
  float f  = u - tf;
  int   t  = (int)tf;
  bool valid = (u >= 0.f) && (u < 11.f);
  t = min(max(t, 0), 10);
  float f2 = f * f, f3 = f2 * f;
  float omf = 1.f - f;
  float v0 = omf * omf * omf;                          // j = t-3
  float v1 = fmaf(f2, fmaf(3.f, f, -6.f), 4.f);        // j = t-2
  float v2 = fmaf(f, fmaf(f, fmaf(-3.f, f, 3.f), 3.f), 1.f);  // j = t-1
  float v3 = f3;                                       // j = t
  uint64_t pack = ((uint64_t)pk2(v2, v3) << 32) | (uint64_t)pk2(v0, v1);
  pack = valid ? pack : 0ull;
  const int base = 48 - 16 * t;                        // in [-112, 48]
  uint4 r;
  r.x = fsh(pack, base);
  r.y = fsh(pack, base + 32);
  r.z = fsh(pack, base + 64);
  r.w = fsh(pack, base + 96);
  return r;
}

// ===========================================================================
// Kernel 1: prep via transpose-through-LDS (R16, coalesced). Blocks 0..511:
// one B-row each; blocks 512..513: per-dim consts.
// Slot mapping (identical to R12-R17): stored slot s = kt*4 + ((c+rot)&3),
// rot=(n>>1)&3; spline kt<128: L = 128c+kt reads coeffs[n][8L..8L+7];
// silu kt>=128: j = 4(kt-128)+c reads bwt[n][8j..8j+7].
// ===========================================================================
__global__ __launch_bounds__(256) void kan_prep_t(
    const float* __restrict__ coeffs,  // (512,4096)
    const float* __restrict__ bwt,     // (512,512)
    const float* __restrict__ gsl,     // (512,11)
    const float* __restrict__ gstart,  // (512,1)
    uint4* __restrict__ B16,           // [512][576]
    float2* __restrict__ cst)          // (512,)
{
  const int bid = blockIdx.x;
  const int tid = threadIdx.x;
  if (bid < 512) {
    __shared__ uint4 T[KCH];           // 9 KB staging, output order
    const int n   = bid;
    const int rot = (n >> 1) & 3;
    #pragma unroll
    for (int h = 0; h < 2; ++h) {
      const int L = tid + h * 256;                     // 0..511
      const float* src = coeffs + (size_t)n * 4096 + L * 8;
      float4 a = *(const float4*)src, b = *(const float4*)(src + 4);
      const int c = L >> 7, kt = L & 127;
      T[kt * 4 + ((c + rot) & 3)] = pk8(a, b);
    }
    if (tid < 64) {
      const float* src = bwt + (size_t)n * 512 + tid * 8;
      float4 a = *(const float4*)src, b = *(const float4*)(src + 4);
      const int kt = 128 + (tid >> 2), c = tid & 3;
      T[kt * 4 + ((c + rot) & 3)] = pk8(a, b);
    }
    __syncthreads();
    uint4* dst = B16 + (size_t)n * KCH;
    for (int i = tid; i < KCH; i += 256) dst[i] = T[i];
  } else {
    const int d = (bid - 512) * 256 + tid;
    if (d < IN_DIM) {
      float v  = gsl[d * 11];                          // all 11 identical
      float sp = fmaxf(v, 0.f) + log1pf(expf(-fabsf(v)));  // softplus = h
      cst[d] = make_float2(gstart[d], 1.f / sp);
    }
  }
}

// ===========================================================================
// Kernel 2: fused basis-gen + GEMM + epilogue. BM=32 x BN=512, G=2, gen-once.
// grid = 512 (XCD-chunked), 256 thr (4 waves). LDS 68KB -> 2 blocks/CU.
// Per group g (tiles 2g, 2g+1):
//   stage 16 gloads/wave + prefetch(g+1) + 1 basis eval/thread -> bar ->
//   2 x [2 af + 8 bg ds_read + 16 MFMA]/wave -> bar.
// ===========================================================================
__device__ __forceinline__ void gload_lds16(const uint4* g, uint4* l) {
  __builtin_amdgcn_global_load_lds(
      (const __attribute__((address_space(1))) void*)g,
      (__attribute__((address_space(3))) void*)l, 16, 0, 0);
}

__global__ __launch_bounds__(256, 2) void kan_fused(
    const float* __restrict__ x,       // (16384,512)
    const uint4* __restrict__ B16,     // [512][576] packed fp16
    const float2* __restrict__ cst,    // (512,) per-dim (g0, 1/h)
    const float* __restrict__ rsc,     // (1,)
    float* __restrict__ out)           // (16384,512)
{
  __shared__ uint4 Bs[2][2048];        // [tile j][512 n-rows][4 chunks] 64 KB
  __shared__ uint4 As[2][128];         // [tile j][32 rows][4 chunks]     4 KB

  const int tid  = threadIdx.x;
  const int lane = tid & 63;
  const int wv   = tid >> 6;

  // XCD-chunked bijective swizzle (512 % 8 == 0): XCD x gets m-panels
  // [x*64, x*64+64).
  const int bid  = blockIdx.x;
  const int wg   = ((bid & 7) << 6) | (bid >> 3);
  const int row0 = wg << 5;            // m-panel * 32

  const int q    = lane >> 4;          // k-chunk 0..3
  const int l15  = lane & 15;
  const int cq   = (q + ((l15 >> 1) & 3)) & 3;   // read-side un-rotation

  // gen mapping: thread = (grow, gc, gpar) = (tid>>3, (tid>>1)&3, tid&1).
  // Per group g: evals dim for tile kt = 2g + gpar, chunk gc, row grow.
  const int gpar  = tid & 1;
  const int gc    = (tid >> 1) & 3;
  const int grow  = tid >> 3;          // 0..31
  const int aslot = grow * 4 + ((gc + (grow >> 1)) & 3);  // rotated As slot
  const float* xrow = x + (size_t)(row0 + grow) * IN_DIM;

  // B staging: wave wv stages Bs slots [wv*512, +512) per tile (rows
  // [wv*128, +128) — exactly what it reads). 8 gload_lds per tile per wave.
  const uint4* gsb[8];
  #pragma unroll
  for (int h = 0; h < 8; ++h) {
    int s = wv * 512 + h * 64 + lane;
    gsb[h] = B16 + (size_t)(s >> 2) * KCH + (s & 3);
  }

  f32x4 acc[2][8];
  #pragma unroll
  for (int a = 0; a < 2; ++a)
    #pragma unroll
    for (int b = 0; b < 8; ++b)
      acc[a][b] = (f32x4){0.f, 0.f, 0.f, 0.f};

  // ---- gen-input registers: current (_c) / next (_n) ----
  float  xs_c, xs_n;
  float2 cf_c, cf_n;
  float4 s0_c, s1_c, s0_n, s1_n;
  {
    const int dim = 128 * gc + gpar;                   // group 0, kt = gpar
    xs_c = xrow[dim];
    cf_c = cst[dim];
  }
  s0_c = s1_c = (float4){0.f, 0.f, 0.f, 0.f};

  // ==== 72 groups of 2 k-tiles: 64 spline + 8 silu ====
  for (int g = 0; g < 72; ++g) {
    // ---- stage group g: 16 gload_lds per wave ----
    #pragma unroll
    for (int j = 0; j < 2; ++j) {
      const int kt = 2 * g + j;
      #pragma unroll
      for (int h = 0; h < 8; ++h)
        gload_lds16(gsb[h] + kt * 4, &Bs[j][wv * 512 + h * 64]);
    }

    // ---- prefetch gen inputs for group g+1 ----
    const int gn = g + 1;
    xs_n = xs_c; cf_n = cf_c; s0_n = s0_c; s1_n = s1_c;
    if (gn < 64) {
      const int dim = 128 * gc + 2 * gn + gpar;
      xs_n = xrow[dim];
      cf_n = cst[dim];
    } else if (gn < 72) {
      const int j0 = 4 * (2 * gn + gpar - 128) + gc;   // 0..63
      s0_n = *(const float4*)(xrow + j0 * 8);
      s1_n = *(const float4*)(xrow + j0 * 8 + 4);
    }

    // ---- gen: ONE eval per thread (gen-once globally), from CURRENT regs --
    if (g < 64)
      As[gpar][aslot] = basis8(xs_c, cf_c.x, cf_c.y);
    else
      As[gpar][aslot] = pk8(silu4(s0_c), silu4(s1_c));
    __syncthreads();                                   // drains vm + lgkm

    // ---- compute 2 tiles: 32 MFMA per wave ----
    #pragma unroll
    for (int j = 0; j < 2; ++j) {
      half8 af[2], bg[8];
      #pragma unroll
      for (int tm = 0; tm < 2; ++tm)
        af[tm] = *(const half8*)&As[j][(tm * 16 + l15) * 4 + cq];
      #pragma unroll
      for (int tn = 0; tn < 8; ++tn)
        bg[tn] = *(const half8*)&Bs[j][(wv * 128 + tn * 16 + l15) * 4 + cq];
      #pragma unroll
      for (int tm = 0; tm < 2; ++tm)
        #pragma unroll
        for (int tn = 0; tn < 8; ++tn)
          acc[tm][tn] = __builtin_amdgcn_mfma_f32_16x16x32_f16(
              af[tm], bg[tn], acc[tm][tn], 0, 0, 0);
    }
    __syncthreads();                                   // protect As/Bs reuse

    xs_c = xs_n; cf_c = cf_n; s0_c = s0_n; s1_c = s1_n;
  }

  // ===== epilogue: + res_scale*x, tanh, store. C/D row=(lane>>4)*4+reg ====
  const float rs = rsc[0];
  #pragma unroll
  for (int tm = 0; tm < 2; ++tm) {
    #pragma unroll
    for (int tn = 0; tn < 8; ++tn) {
      #pragma unroll
      for (int r = 0; r < 4; ++r) {
        int m = row0 + tm * 16 + q * 4 + r;
        int n = wv * 128 + tn * 16 + l15;
        float xg = x[(size_t)m * IN_DIM + n];
        float y  = acc[tm][tn][r] + rs * xg;
        float e  = __expf(-2.f * fabsf(y));
        float t  = copysignf((1.f - e) / (1.f + e), y);
        out[(size_t)m * OUT_DIM + n] = t;
      }
    }
  }
}

// ===========================================================================
// Fallback: verified R5 fused kernel (used only if workspace is too small).
// ===========================================================================
__device__ __forceinline__ int swz(int r, int c) {
  return r * 4 + ((c + (r >> 1)) & 3);
}

__global__ __launch_bounds__(256, 2) void kan_main(
    const float* __restrict__ x, const float* __restrict__ coeffs,
    const float* __restrict__ bwt, const float* __restrict__ gsl,
    const float* __restrict__ gstart, const float* __restrict__ rsc,
    float* __restrict__ out)
{
  __shared__ uint4 At[512];
  __shared__ uint4 Bt[512];
  __shared__ float2 Cs[512];

  const int tid  = threadIdx.x;
  const int lane = tid & 63;
  const int wv   = tid >> 6;
  const int row0 = blockIdx.y << 7;
  const int n0   = blockIdx.x << 7;

  const int q    = lane >> 4;
  const int l15  = lane & 15;
  const int wrow = (wv >> 1) << 6;
  const int wcol = (wv & 1) << 6;

  for (int d = tid; d < IN_DIM; d += 256) {
    float v  = gsl[d * 11];
    float sp = fmaxf(v, 0.f) + log1pf(expf(-fabsf(v)));
    Cs[d] = make_float2(gstart[d], 1.f / sp);
  }
  __syncthreads();

  f32x4 acc[4][4];
  #pragma unroll
  for (int a = 0; a < 4; ++a)
    #pragma unroll
    for (int b = 0; b < 4; ++b)
      acc[a][b] = (f32x4){0.f, 0.f, 0.f, 0.f};

  const int br0 = tid >> 2,        bc0 = tid & 3;
  const int br1 = (tid + 256) >> 2, bc1 = tid & 3;

  auto do_mfma = [&]() {
    half8 af[4], bg[4];
    #pragma unroll
    for (int tm = 0; tm < 4; ++tm) {
      int m = wrow + tm * 16 + l15;
      af[tm] = *(const half8*)&At[swz(m, q)];
    }
    #pragma unroll
    for (int tn = 0; tn < 4; ++tn) {
      int n = wcol + tn * 16 + l15;
      bg[tn] = *(const half8*)&Bt[swz(n, q)];
    }
    #pragma unroll
    for (int tm = 0; tm < 4; ++tm)
      #pragma unroll
      for (int tn = 0; tn < 4; ++tn)
        acc[tm][tn] = __builtin_amdgcn_mfma_f32_16x16x32_f16(
            af[tm], bg[tn], acc[tm][tn], 0, 0, 0);
  };

  const float* bp0 = coeffs + (size_t)(n0 + br0) * 4096 + 1024 * bc0;
  const float* bp1 = coeffs + (size_t)(n0 + br1) * 4096 + 1024 * bc1;
  const float* xp0 = x + (size_t)(row0 + lane) * IN_DIM + 128 * wv;
  const float* xp1 = xp0 + (size_t)64 * IN_DIM;

  for (int kt4 = 0; kt4 < 32; ++kt4) {
    float4 xa = *(const float4*)(xp0 + kt4 * 4);
    float4 xb = *(const float4*)(xp1 + kt4 * 4);
    float xr0[4] = {xa.x, xa.y, xa.z, xa.w};
    float xr1[4] = {xb.x, xb.y, xb.z, xb.w};
    #pragma unroll
    for (int j = 0; j < 4; ++j) {
      const int kt = kt4 * 4 + j;
      const float* s0 = bp0 + kt * 8;
      const float* s1 = bp1 + kt * 8;
      float4 b0a = *(const float4*)(s0), b0b = *(const float4*)(s0 + 4);
      float4 b1a = *(const float4*)(s1), b1b = *(const float4*)(s1 + 4);

      float2 c = Cs[128 * wv + kt];
      uint4 p0 = basis8(xr0[j], c.x, c.y);
      uint4 p1 = basis8(xr1[j], c.x, c.y);

      Bt[swz(br0, bc0)] = pk8(b0a, b0b);
      Bt[swz(br1, bc1)] = pk8(b1a, b1b);
      At[swz(lane, wv)]      = p0;
      At[swz(lane + 64, wv)] = p1;
      __syncthreads();
      do_mfma();
      __syncthreads();
    }
  }

  for (int kt = 0; kt < 16; ++kt) {
    const int k0 = kt * 32;
    const float* s0 = bwt + (size_t)(n0 + br0) * 512 + k0 + bc0 * 8;
    const float* s1 = bwt + (size_t)(n0 + br1) * 512 + k0 + bc1 * 8;
    float4 b0a = *(const float4*)(s0), b0b = *(const float4*)(s0 + 4);
    float4 b1a = *(const float4*)(s1), b1b = *(const float4*)(s1 + 4);

    uint4 p[2];
    #pragma unroll
    for (int rr = 0; rr < 2; ++rr) {
      int idx = tid + rr * 256;
      int r = idx >> 2, cch = idx & 3;
      const float* xs = x + (size_t)(row0 + r) * IN_DIM + k0 + cch * 8;
      float4 xc = *(const float4*)(xs), xd = *(const float4*)(xs + 4);
      float f[8] = {xc.x, xc.y, xc.z, xc.w, xd.x, xd.y, xd.z, xd.w};
      #pragma unroll
      for (int jj = 0; jj < 8; ++jj) f[jj] = f[jj] / (1.f + __expf(-f[jj]));
      p[rr].x = pk2(f[0], f[1]); p[rr].y = pk2(f[2], f[3]);
      p[rr].z = pk2(f[4], f[5]); p[rr].w = pk2(f[6], f[7]);
    }

    Bt[swz(br0, bc0)] = pk8(b0a, b0b);
    Bt[swz(br1, bc1)] = pk8(b1a, b1b);
    #pragma unroll
    for (int rr = 0; rr < 2; ++rr) {
      int idx = tid + rr * 256;
      At[swz(idx >> 2, idx & 3)] = p[rr];
    }
    __syncthreads();
    do_mfma();
    __syncthreads();
  }

  const float rs = rsc[0];
  #pragma unroll
  for (int tm = 0; tm < 4; ++tm) {
    #pragma unroll
    for (int tn = 0; tn < 4; ++tn) {
      #pragma unroll
      for (int r = 0; r < 4; ++r) {
        int m = row0 + wrow + tm * 16 + q * 4 + r;
        int n = n0 + wcol + tn * 16 + l15;
        float xv = x[(size_t)m * IN_DIM + n];
        float y  = acc[tm][tn][r] + rs * xv;
        float e  = __expf(-2.f * fabsf(y));
        float t  = copysignf((1.f - e) / (1.f + e), y);
        out[(size_t)m * OUT_DIM + n] = t;
      }
    }
  }
}

// ---------------------------------------------------------------------------
extern "C" void kernel_launch(void* const* d_in, const int* in_sizes, int n_in,
                              void* d_out, int out_size, void* d_ws, size_t ws_size,
                              hipStream_t stream) {
  const float* x      = (const float*)d_in[0];
  const float* coeffs = (const float*)d_in[1];
  const float* bwt    = (const float*)d_in[2];
  const float* gsl    = (const float*)d_in[3];
  const float* gstart = (const float*)d_in[4];
  const float* rsc    = (const float*)d_in[5];
  float* out = (float*)d_out;
  (void)in_sizes; (void)n_in; (void)out_size;

  const size_t needB = (size_t)OUT_DIM * KCH * 16;   // 4,718,592 B
  const size_t needC = (size_t)IN_DIM * 8;           //     4,096 B

  if (d_ws != nullptr && ws_size >= needB + needC) {
    uint4*  B16 = (uint4*)d_ws;
    float2* cst = (float2*)((char*)d_ws + needB);
    hipLaunchKernelGGL(kan_prep_t, dim3(514), dim3(256), 0, stream,
                       coeffs, bwt, gsl, gstart, B16, cst);
    hipLaunchKernelGGL(kan_fused, dim3(512), dim3(256), 0, stream,
                       x, (const uint4*)B16, (const float2*)cst, rsc, out);
  } else {
    hipLaunchKernelGGL(kan_main, dim3(4, 128), dim3(256), 0, stream,
                       x, coeffs, bwt, gsl, gstart, rsc, out);
  }
}

// Round 18
// 210.994 us; speedup vs baseline: 1.4207x; 1.4207x over previous
//
#include <hip/hip_runtime.h>
#include <stdint.h>
#include <stddef.h>

// ---------------------------------------------------------------------------
// BSplineKANLayer — R19: REVERT to best-measured config (R16; total 211.1us,
// R15-equivalent 210.3us — equal within noise).
// R18 post-mortem: BM=32 gen-once = 232us regression (staging-per-MFMA
// doubled: 64KB staged per group for 128 MFMA vs R12's 256; MfmaUtil 13.7).
// Completed quadrant table across R10-R18: BM64xBN256/G=4/2blk-CU with the
// plain 2-barrier schedule (R12/R15/R16, 141-142.6us) beats every structural
// alternative tested (dbuf x2, counted-vmcnt x2, G in {2,4}, BM in {32,64},
// BN in {256,512}, blocks/CU in {1,2}). MFMA busy ~33us and stall ~45-50us
// are schedule-invariant; gen VALU ~61us is the fused kernel's cost of
// avoiding the 151MB A16 round-trip (split design measured 214-245us).
// ---------------------------------------------------------------------------

typedef __attribute__((ext_vector_type(8))) _Float16 half8;  // 8 fp16 = 4 VGPRs
typedef __attribute__((ext_vector_type(4))) float f32x4;

#define IN_DIM   512
#define OUT_DIM  512
#define BATCH    16384
#define KCH      576     // uint4 chunks per row: 4608 fp16 = 576 * 16B

// RNE f32 -> fp16 pair packed in a uint (a low 16, b high 16)
__device__ __forceinline__ unsigned pk2(float a, float b) {
  _Float16 ha = (_Float16)a, hb = (_Float16)b;   // v_cvt_f16_f32 (RNE)
  unsigned short ua = __builtin_bit_cast(unsigned short, ha);
  unsigned short ub = __builtin_bit_cast(unsigned short, hb);
  return (unsigned)ua | ((unsigned)ub << 16);
}
__device__ __forceinline__ uint4 pk8(float4 a, float4 b) {
  uint4 r;
  r.x = pk2(a.x, a.y); r.y = pk2(a.z, a.w);
  r.z = pk2(b.x, b.y); r.w = pk2(b.z, b.w);
  return r;
}
__device__ __forceinline__ float4 silu4(float4 v) {
  float4 r;
  r.x = v.x / (1.f + __expf(-v.x));
  r.y = v.y / (1.f + __expf(-v.y));
  r.z = v.z / (1.f + __expf(-v.z));
  r.w = v.w / (1.f + __expf(-v.w));
  return r;
}

// branchless 64->32 funnel extract: bits [amt, amt+32) of p, 0 outside range
__device__ __forceinline__ uint32_t fsh(uint64_t p, int amt) {
  uint32_t lo = (uint32_t)(p >> (amt & 63));
  lo = (amt >= 0 && amt < 64) ? lo : 0u;
  uint32_t hi = (uint32_t)(p << ((-amt) & 63));
  hi = (amt < 0 && amt > -64) ? hi : 0u;
  return lo | hi;
}

// Windowed cubic basis (uniform grid; matches reference's single-step-denom
// recursion exactly — verified R5..R18): 8 fp16 values for one (row,dim).
__device__ __forceinline__ uint4 basis8(float xv, float g0, float rh) {
  float u  = (xv - g0) * rh;
  float tf = floorf(u);
  float f  = u - tf;
  int   t  = (int)tf;
  bool valid = (u >= 0.f) && (u < 11.f);
  t = min(max(t, 0), 10);
  float f2 = f * f, f3 = f2 * f;
  float omf = 1.f - f;
  float v0 = omf * omf * omf;                          // j = t-3
  float v1 = fmaf(f2, fmaf(3.f, f, -6.f), 4.f);        // j = t-2
  float v2 = fmaf(f, fmaf(f, fmaf(-3.f, f, 3.f), 3.f), 1.f);  // j = t-1
  float v3 = f3;                                       // j = t
  uint64_t pack = ((uint64_t)pk2(v2, v3) << 32) | (uint64_t)pk2(v0, v1);
  pack = valid ? pack : 0ull;
  const int base = 48 - 16 * t;                        // in [-112, 48]
  uint4 r;
  r.x = fsh(pack, base);
  r.y = fsh(pack, base + 32);
  r.z = fsh(pack, base + 64);
  r.w = fsh(pack, base + 96);
  return r;
}

// ===========================================================================
// Kernel 1: prep via transpose-through-LDS (coalesced). Blocks 0..511: one
// B-row each; blocks 512..513: per-dim consts.
// Slot mapping (identical to R12-R18): stored slot s = kt*4 + ((c+rot)&3),
// rot=(n>>1)&3; spline kt<128: L = 128c+kt reads coeffs[n][8L..8L+7];
// silu kt>=128: j = 4(kt-128)+c reads bwt[n][8j..8j+7].
// ===========================================================================
__global__ __launch_bounds__(256) void kan_prep_t(
    const float* __restrict__ coeffs,  // (512,4096)
    const float* __restrict__ bwt,     // (512,512)
    const float* __restrict__ gsl,     // (512,11)
    const float* __restrict__ gstart,  // (512,1)
    uint4* __restrict__ B16,           // [512][576]
    float2* __restrict__ cst)          // (512,)
{
  const int bid = blockIdx.x;
  const int tid = threadIdx.x;
  if (bid < 512) {
    __shared__ uint4 T[KCH];           // 9 KB staging, output order
    const int n   = bid;
    const int rot = (n >> 1) & 3;
    #pragma unroll
    for (int h = 0; h < 2; ++h) {
      const int L = tid + h * 256;                     // 0..511
      const float* src = coeffs + (size_t)n * 4096 + L * 8;
      float4 a = *(const float4*)src, b = *(const float4*)(src + 4);
      const int c = L >> 7, kt = L & 127;
      T[kt * 4 + ((c + rot) & 3)] = pk8(a, b);
    }
    if (tid < 64) {
      const float* src = bwt + (size_t)n * 512 + tid * 8;
      float4 a = *(const float4*)src, b = *(const float4*)(src + 4);
      const int kt = 128 + (tid >> 2), c = tid & 3;
      T[kt * 4 + ((c + rot) & 3)] = pk8(a, b);
    }
    __syncthreads();
    uint4* dst = B16 + (size_t)n * KCH;
    for (int i = tid; i < KCH; i += 256) dst[i] = T[i];
  } else {
    const int d = (bid - 512) * 256 + tid;
    if (d < IN_DIM) {
      float v  = gsl[d * 11];                          // all 11 identical
      float sp = fmaxf(v, 0.f) + log1pf(expf(-fabsf(v)));  // softplus = h
      cst[d] = make_float2(gstart[d], 1.f / sp);
    }
  }
}

// ===========================================================================
// Kernel 2: fused basis-gen + GEMM + epilogue. BM=64 x BN=256, G=4.
// grid = 512 (XCD-chunked), 256 thr (4 waves). LDS 80KB -> 2 blocks/CU.
// Per group: stage 16 gloads + prefetch spline inputs for g+1 + gen 4 evals
// -> bar -> 4x[ds_read + 16 MFMA] -> bar. (Best-measured: 141-142.6us.)
// ===========================================================================
__device__ __forceinline__ void gload_lds16(const uint4* g, uint4* l) {
  __builtin_amdgcn_global_load_lds(
      (const __attribute__((address_space(1))) void*)g,
      (__attribute__((address_space(3))) void*)l, 16, 0, 0);
}

__global__ __launch_bounds__(256, 2) void kan_fused(
    const float* __restrict__ x,       // (16384,512)
    const uint4* __restrict__ B16,     // [512][576] packed fp16
    const float2* __restrict__ cst,    // (512,) per-dim (g0, 1/h)
    const float* __restrict__ rsc,     // (1,)
    float* __restrict__ out)           // (16384,512)
{
  __shared__ uint4 Bs[4][1024];        // [j][256 n-rows][4 chunks] = 64 KB
  __shared__ uint4 As[4][256];         // [j][64 rows][4 chunks]    = 16 KB

  const int tid  = threadIdx.x;
  const int lane = tid & 63;
  const int wv   = tid >> 6;

  // XCD-chunked bijective swizzle (512 % 8 == 0).
  const int bid  = blockIdx.x;
  const int wg   = ((bid & 7) << 6) | (bid >> 3);
  const int row0 = (wg >> 1) << 6;     // m-panel * 64
  const int n0   = (wg & 1) << 8;      // n-half * 256

  const int q    = lane >> 4;          // k-chunk 0..3
  const int l15  = lane & 15;
  const int cq   = (q + ((l15 >> 1) & 3)) & 3;   // read-side un-rotation

  // A-gen mapping: thread (grow, gc) = (tid>>2, tid&3), 4 evals per group
  const int grow  = tid >> 2;          // 0..63 local row
  const int gc    = tid & 3;           // logical chunk
  const int aslot = grow * 4 + ((gc + (grow >> 1)) & 3);  // rotated As slot
  const float* xrow = x + (size_t)(row0 + grow) * IN_DIM;

  // B staging: wave wv fills Bs slots [wv*64 + h*256, +64), h=0..3
  const uint4* gsb[4];
  #pragma unroll
  for (int h = 0; h < 4; ++h) {
    int s = wv * 64 + h * 256 + lane;
    gsb[h] = B16 + (size_t)(n0 + (s >> 2)) * KCH + (s & 3);
  }

  f32x4 acc[4][4];
  #pragma unroll
  for (int a = 0; a < 4; ++a)
    #pragma unroll
    for (int b = 0; b < 4; ++b)
      acc[a][b] = (f32x4){0.f, 0.f, 0.f, 0.f};

  // ---- spline gen-input prefetch registers, loaded for group 0 ----
  float4 xv_c, c01_c, c23_c;
  {
    const int d0 = 128 * gc;                           // group 0 dims
    xv_c  = *(const float4*)(xrow + d0);
    c01_c = *(const float4*)(cst + d0);
    c23_c = *(const float4*)(cst + d0 + 2);
  }

  // ==== 36 groups of 4 k-tiles: 32 spline + 4 silu ====
  for (int g = 0; g < 36; ++g) {
    // ---- stage 4 B-tiles (16 gloads) ----
    #pragma unroll
    for (int j = 0; j < 4; ++j) {
      const int kt = g * 4 + j;
      #pragma unroll
      for (int h = 0; h < 4; ++h)
        gload_lds16(gsb[h] + kt * 4, &Bs[j][wv * 64 + h * 256]);
    }

    // ---- prefetch spline gen inputs for group g+1 ----
    float4 xv_n = {0.f, 0.f, 0.f, 0.f};
    float4 c01_n = xv_n, c23_n = xv_n;
    const int gn = g + 1;
    if (gn < 32) {
      const int d0 = 128 * gc + gn * 4;
      xv_n  = *(const float4*)(xrow + d0);
      c01_n = *(const float4*)(cst + d0);
      c23_n = *(const float4*)(cst + d0 + 2);
    }

    // ---- gen 4 A-tiles ----
    if (g < 32) {
      // from CURRENT regs (no load-to-use chain)
      As[0][aslot] = basis8(xv_c.x, c01_c.x, c01_c.y);
      As[1][aslot] = basis8(xv_c.y, c01_c.z, c01_c.w);
      As[2][aslot] = basis8(xv_c.z, c23_c.x, c23_c.y);
      As[3][aslot] = basis8(xv_c.w, c23_c.z, c23_c.w);
    } else {
      // 4 silu groups of 36: direct loads (small, bounded stall)
      #pragma unroll
      for (int j = 0; j < 4; ++j) {
        const int kp = (g - 32) * 4 + j;               // 0..15
        const float* xs = xrow + (4 * kp + gc) * 8;
        float4 a_ = *(const float4*)(xs), b_ = *(const float4*)(xs + 4);
        As[j][aslot] = pk8(silu4(a_), silu4(b_));
      }
    }
    __syncthreads();                                   // drains vm + lgkm

    // ---- compute 4 tiles: 64 MFMA ----
    #pragma unroll
    for (int j = 0; j < 4; ++j) {
      half8 af[4], bg[4];
      #pragma unroll
      for (int tm = 0; tm < 4; ++tm)
        af[tm] = *(const half8*)&As[j][(tm * 16 + l15) * 4 + cq];
      #pragma unroll
      for (int tn = 0; tn < 4; ++tn)
        bg[tn] = *(const half8*)&Bs[j][(wv * 64 + tn * 16 + l15) * 4 + cq];
      #pragma unroll
      for (int tm = 0; tm < 4; ++tm)
        #pragma unroll
        for (int tn = 0; tn < 4; ++tn)
          acc[tm][tn] = __builtin_amdgcn_mfma_f32_16x16x32_f16(
              af[tm], bg[tn], acc[tm][tn], 0, 0, 0);
    }
    __syncthreads();                                   // protect As/Bs reuse

    xv_c = xv_n; c01_c = c01_n; c23_c = c23_n;
  }

  // ===== epilogue: + res_scale*x, tanh, store. C/D row=(lane>>4)*4+reg ====
  const float rs = rsc[0];
  #pragma unroll
  for (int tm = 0; tm < 4; ++tm) {
    #pragma unroll
    for (int tn = 0; tn < 4; ++tn) {
      #pragma unroll
      for (int r = 0; r < 4; ++r) {
        int m = row0 + tm * 16 + q * 4 + r;
        int n = n0 + wv * 64 + tn * 16 + l15;
        float xg = x[(size_t)m * IN_DIM + n];
        float y  = acc[tm][tn][r] + rs * xg;
        float e  = __expf(-2.f * fabsf(y));
        float t  = copysignf((1.f - e) / (1.f + e), y);
        out[(size_t)m * OUT_DIM + n] = t;
      }
    }
  }
}

// ===========================================================================
// Fallback: verified R5 fused kernel (used only if workspace is too small).
// ===========================================================================
__device__ __forceinline__ int swz(int r, int c) {
  return r * 4 + ((c + (r >> 1)) & 3);
}

__global__ __launch_bounds__(256, 2) void kan_main(
    const float* __restrict__ x, const float* __restrict__ coeffs,
    const float* __restrict__ bwt, const float* __restrict__ gsl,
    const float* __restrict__ gstart, const float* __restrict__ rsc,
    float* __restrict__ out)
{
  __shared__ uint4 At[512];
  __shared__ uint4 Bt[512];
  __shared__ float2 Cs[512];

  const int tid  = threadIdx.x;
  const int lane = tid & 63;
  const int wv   = tid >> 6;
  const int row0 = blockIdx.y << 7;
  const int n0   = blockIdx.x << 7;

  const int q    = lane >> 4;
  const int l15  = lane & 15;
  const int wrow = (wv >> 1) << 6;
  const int wcol = (wv & 1) << 6;

  for (int d = tid; d < IN_DIM; d += 256) {
    float v  = gsl[d * 11];
    float sp = fmaxf(v, 0.f) + log1pf(expf(-fabsf(v)));
    Cs[d] = make_float2(gstart[d], 1.f / sp);
  }
  __syncthreads();

  f32x4 acc[4][4];
  #pragma unroll
  for (int a = 0; a < 4; ++a)
    #pragma unroll
    for (int b = 0; b < 4; ++b)
      acc[a][b] = (f32x4){0.f, 0.f, 0.f, 0.f};

  const int br0 = tid >> 2,        bc0 = tid & 3;
  const int br1 = (tid + 256) >> 2, bc1 = tid & 3;

  auto do_mfma = [&]() {
    half8 af[4], bg[4];
    #pragma unroll
    for (int tm = 0; tm < 4; ++tm) {
      int m = wrow + tm * 16 + l15;
      af[tm] = *(const half8*)&At[swz(m, q)];
    }
    #pragma unroll
    for (int tn = 0; tn < 4; ++tn) {
      int n = wcol + tn * 16 + l15;
      bg[tn] = *(const half8*)&Bt[swz(n, q)];
    }
    #pragma unroll
    for (int tm = 0; tm < 4; ++tm)
      #pragma unroll
      for (int tn = 0; tn < 4; ++tn)
        acc[tm][tn] = __builtin_amdgcn_mfma_f32_16x16x32_f16(
            af[tm], bg[tn], acc[tm][tn], 0, 0, 0);
  };

  const float* bp0 = coeffs + (size_t)(n0 + br0) * 4096 + 1024 * bc0;
  const float* bp1 = coeffs + (size_t)(n0 + br1) * 4096 + 1024 * bc1;
  const float* xp0 = x + (size_t)(row0 + lane) * IN_DIM + 128 * wv;
  const float* xp1 = xp0 + (size_t)64 * IN_DIM;

  for (int kt4 = 0; kt4 < 32; ++kt4) {
    float4 xa = *(const float4*)(xp0 + kt4 * 4);
    float4 xb = *(const float4*)(xp1 + kt4 * 4);
    float xr0[4] = {xa.x, xa.y, xa.z, xa.w};
    float xr1[4] = {xb.x, xb.y, xb.z, xb.w};
    #pragma unroll
    for (int j = 0; j < 4; ++j) {
      const int kt = kt4 * 4 + j;
      const float* s0 = bp0 + kt * 8;
      const float* s1 = bp1 + kt * 8;
      float4 b0a = *(const float4*)(s0), b0b = *(const float4*)(s0 + 4);
      float4 b1a = *(const float4*)(s1), b1b = *(const float4*)(s1 + 4);

      float2 c = Cs[128 * wv + kt];
      uint4 p0 = basis8(xr0[j], c.x, c.y);
      uint4 p1 = basis8(xr1[j], c.x, c.y);

      Bt[swz(br0, bc0)] = pk8(b0a, b0b);
      Bt[swz(br1, bc1)] = pk8(b1a, b1b);
      At[swz(lane, wv)]      = p0;
      At[swz(lane + 64, wv)] = p1;
      __syncthreads();
      do_mfma();
      __syncthreads();
    }
  }

  for (int kt = 0; kt < 16; ++kt) {
    const int k0 = kt * 32;
    const float* s0 = bwt + (size_t)(n0 + br0) * 512 + k0 + bc0 * 8;
    const float* s1 = bwt + (size_t)(n0 + br1) * 512 + k0 + bc1 * 8;
    float4 b0a = *(const float4*)(s0), b0b = *(const float4*)(s0 + 4);
    float4 b1a = *(const float4*)(s1), b1b = *(const float4*)(s1 + 4);

    uint4 p[2];
    #pragma unroll
    for (int rr = 0; rr < 2; ++rr) {
      int idx = tid + rr * 256;
      int r = idx >> 2, cch = idx & 3;
      const float* xs = x + (size_t)(row0 + r) * IN_DIM + k0 + cch * 8;
      float4 xc = *(const float4*)(xs), xd = *(const float4*)(xs + 4);
      float f[8] = {xc.x, xc.y, xc.z, xc.w, xd.x, xd.y, xd.z, xd.w};
      #pragma unroll
      for (int jj = 0; jj < 8; ++jj) f[jj] = f[jj] / (1.f + __expf(-f[jj]));
      p[rr].x = pk2(f[0], f[1]); p[rr].y = pk2(f[2], f[3]);
      p[rr].z = pk2(f[4], f[5]); p[rr].w = pk2(f[6], f[7]);
    }

    Bt[swz(br0, bc0)] = pk8(b0a, b0b);
    Bt[swz(br1, bc1)] = pk8(b1a, b1b);
    #pragma unroll
    for (int rr = 0; rr < 2; ++rr) {
      int idx = tid + rr * 256;
      At[swz(idx >> 2, idx & 3)] = p[rr];
    }
    __syncthreads();
    do_mfma();
    __syncthreads();
  }

  const float rs = rsc[0];
  #pragma unroll
  for (int tm = 0; tm < 4; ++tm) {
    #pragma unroll
    for (int tn = 0; tn < 4; ++tn) {
      #pragma unroll
      for (int r = 0; r < 4; ++r) {
        int m = row0 + wrow + tm * 16 + q * 4 + r;
        int n = n0 + wcol + tn * 16 + l15;
        float xv = x[(size_t)m * IN_DIM + n];
        float y  = acc[tm][tn][r] + rs * xv;
        float e  = __expf(-2.f * fabsf(y));
        float t  = copysignf((1.f - e) / (1.f + e), y);
        out[(size_t)m * OUT_DIM + n] = t;
      }
    }
  }
}

// ---------------------------------------------------------------------------
extern "C" void kernel_launch(void* const* d_in, const int* in_sizes, int n_in,
                              void* d_out, int out_size, void* d_ws, size_t ws_size,
                              hipStream_t stream) {
  const float* x      = (const float*)d_in[0];
  const float* coeffs = (const float*)d_in[1];
  const float* bwt    = (const float*)d_in[2];
  const float* gsl    = (const float*)d_in[3];
  const float* gstart = (const float*)d_in[4];
  const float* rsc    = (const float*)d_in[5];
  float* out = (float*)d_out;
  (void)in_sizes; (void)n_in; (void)out_size;

  const size_t needB = (size_t)OUT_DIM * KCH * 16;   // 4,718,592 B
  const size_t needC = (size_t)IN_DIM * 8;           //     4,096 B

  if (d_ws != nullptr && ws_size >= needB + needC) {
    uint4*  B16 = (uint4*)d_ws;
    float2* cst = (float2*)((char*)d_ws + needB);
    hipLaunchKernelGGL(kan_prep_t, dim3(514), dim3(256), 0, stream,
                       coeffs, bwt, gsl, gstart, B16, cst);
    hipLaunchKernelGGL(kan_fused, dim3(512), dim3(256), 0, stream,
                       x, (const uint4*)B16, (const float2*)cst, rsc, out);
  } else {
    hipLaunchKernelGGL(kan_main, dim3(4, 128), dim3(256), 0, stream,
                       x, coeffs, bwt, gsl, gstart, rsc, out);
  }
}